// Round 1
// baseline (232.897 us; speedup 1.0000x reference)
//
#include <hip/hip_runtime.h>
#include <hip/hip_bf16.h>

// Fused adapter: out = relu(LN(x) @ Wd + bd) @ Wu + bu
// LN folded into GEMM1:  down = rs*(x @ (gamma⊙Wd)) - rs*mu*s + t
//   s[k] = sum_d gamma[d]*Wd[d][k];  t[k] = sum_d beta[d]*Wd[d][k] + bd[k]
// bf16 MFMA (16x16x32) for both GEMMs; x staged bf16 in LDS.
// NOTE: w_up==0 in this input set => reference output is exactly 0, so the
// harness cannot catch MFMA-layout mistakes; layouts follow the m89-verified
// C/D mapping (col=lane&15, row=(lane>>4)*4+reg) and standard A/B mapping
// (row/col = lane%16, k = 8*(lane>>4)+e).

#define D_MODEL 768
#define KB      64
#define BM      32      // rows per block
#define NTHR    256     // 4 waves

typedef __attribute__((ext_vector_type(8))) short    bf16x8;
typedef __attribute__((ext_vector_type(4))) float    f32x4;
typedef __attribute__((ext_vector_type(4))) unsigned short us4;

static __device__ __forceinline__ unsigned short f2bf(float f) {
  // round-to-nearest-even f32 -> bf16 (inputs are finite)
  unsigned int u = __builtin_bit_cast(unsigned int, f);
  unsigned int r = u + 0x7FFFu + ((u >> 16) & 1u);
  return (unsigned short)(r >> 16);
}

// ---------------- prep kernel: transform weights into d_ws ----------------
// wdT[k][d] = bf16(gamma[d] * Wd[d][k])   (64 x 768)
// wuT[d][k] = bf16(Wu[k][d])              (768 x 64)
// s[k] = sum_d gamma[d]*Wd[d][k];  t[k] = sum_d beta[d]*Wd[d][k] + bd[k]
__global__ void adapter_prep(const float* __restrict__ wd,
                             const float* __restrict__ wu,
                             const float* __restrict__ gamma,
                             const float* __restrict__ beta,
                             const float* __restrict__ bdown,
                             unsigned short* __restrict__ wdT,
                             unsigned short* __restrict__ wuT,
                             float* __restrict__ s_arr,
                             float* __restrict__ t_arr) {
  const int k = threadIdx.x;            // 0..63
  const int b = blockIdx.x;             // 0..768
  if (b < D_MODEL) {
    const int d = b;
    const float g = gamma[d];
    wdT[(size_t)k * D_MODEL + d] = f2bf(g * wd[(size_t)d * KB + k]);
    wuT[(size_t)d * KB + k]      = f2bf(wu[(size_t)k * D_MODEL + d]);
  } else {
    float ss = 0.f, tt = 0.f;
    for (int d = 0; d < D_MODEL; ++d) {
      const float w = wd[(size_t)d * KB + k];
      ss = fmaf(gamma[d], w, ss);
      tt = fmaf(beta[d],  w, tt);
    }
    s_arr[k] = ss;
    t_arr[k] = tt + bdown[k];
  }
}

// ---------------- main fused kernel ----------------
#define XPAD 776   // 768 + 8 bf16 pad: row stride 1552 B -> bank+4/row (2-way, free)
#define PPAD 72    // 64 + 8 pad

__global__ void __launch_bounds__(NTHR) adapter_main(
    const float* __restrict__ x,
    const float* __restrict__ s_arr,
    const float* __restrict__ t_arr,
    const unsigned short* __restrict__ wdT,
    const unsigned short* __restrict__ wuT,
    const float* __restrict__ b_up,
    float* __restrict__ out) {

  __shared__ unsigned short x_s[BM * XPAD];   // 48.5 KiB: raw x as bf16
  __shared__ unsigned short p_s[BM * PPAD];   //  4.5 KiB: relu(down) as bf16
  __shared__ float mu_s[BM];
  __shared__ float rs_s[BM];

  const int t    = threadIdx.x;
  const int row0 = blockIdx.x * BM;

  // ---- Phase 1: load x tile (coalesced f32x4), row stats, stage bf16 ----
  {
    const int r  = t >> 3;          // 8 threads per row
    const int c0 = (t & 7) * 4;     // float4 base col, stride 32
    const float* xp = x + (size_t)(row0 + r) * D_MODEL;
    float s1 = 0.f, s2 = 0.f;
    #pragma unroll
    for (int i = 0; i < 24; ++i) {
      const int c = c0 + 32 * i;
      const float4 v = *(const float4*)(xp + c);
      s1 += v.x + v.y + v.z + v.w;
      s2 = fmaf(v.x, v.x, s2); s2 = fmaf(v.y, v.y, s2);
      s2 = fmaf(v.z, v.z, s2); s2 = fmaf(v.w, v.w, s2);
      us4 pk;
      pk.x = f2bf(v.x); pk.y = f2bf(v.y); pk.z = f2bf(v.z); pk.w = f2bf(v.w);
      *(us4*)&x_s[r * XPAD + c] = pk;   // ds_write_b64
    }
    // reduce over the 8 lanes sharing this row (adjacent lanes)
    s1 += __shfl_xor(s1, 1); s2 += __shfl_xor(s2, 1);
    s1 += __shfl_xor(s1, 2); s2 += __shfl_xor(s2, 2);
    s1 += __shfl_xor(s1, 4); s2 += __shfl_xor(s2, 4);
    const float mean = s1 * (1.0f / 768.0f);
    const float var  = s2 * (1.0f / 768.0f) - mean * mean;
    if ((t & 7) == 0) {
      mu_s[r] = mean;
      rs_s[r] = rsqrtf(var + 1e-5f);
    }
  }
  __syncthreads();

  const int w  = t >> 6;       // wave 0..3
  const int l  = t & 63;
  const int lr = l & 15;       // fragment row/col lane index
  const int lg = l >> 4;       // k-group

  // ---- Phase 2: GEMM1 (x[32x768] @ WdT-as-B[768x64]); wave w owns cols 16w..16w+15 ----
  {
    const int cw = 16 * w;
    f32x4 acc0 = {0.f, 0.f, 0.f, 0.f};
    f32x4 acc1 = {0.f, 0.f, 0.f, 0.f};
    const unsigned short* bp = wdT + (size_t)(cw + lr) * D_MODEL + 8 * lg;
    #pragma unroll
    for (int kk = 0; kk < 24; ++kk) {
      const bf16x8 bq = *(const bf16x8*)(bp + 32 * kk);
      const bf16x8 a0 = *(const bf16x8*)&x_s[lr * XPAD + 32 * kk + 8 * lg];
      const bf16x8 a1 = *(const bf16x8*)&x_s[(16 + lr) * XPAD + 32 * kk + 8 * lg];
      acc0 = __builtin_amdgcn_mfma_f32_16x16x32_bf16(a0, bq, acc0, 0, 0, 0);
      acc1 = __builtin_amdgcn_mfma_f32_16x16x32_bf16(a1, bq, acc1, 0, 0, 0);
    }
    const float sk = s_arr[cw + lr];
    const float tk = t_arr[cw + lr];
    #pragma unroll
    for (int m = 0; m < 2; ++m) {
      #pragma unroll
      for (int j = 0; j < 4; ++j) {
        const int r = 16 * m + 4 * lg + j;            // D row = (lane>>4)*4 + reg
        const float rs = rs_s[r], mu = mu_s[r];
        const float q  = (m == 0) ? acc0[j] : acc1[j];
        float dn = fmaf(rs, q, fmaf(-rs * mu, sk, tk));
        dn = fmaxf(dn, 0.0f);                          // ReLU
        p_s[r * PPAD + cw + lr] = f2bf(dn);
      }
    }
  }
  __syncthreads();

  // ---- Phase 3: GEMM2 (P[32x64] @ WuT-as-B[64x768]); wave w owns N-tiles 12w..12w+11 ----
  {
    bf16x8 pa[2][2];
    #pragma unroll
    for (int m = 0; m < 2; ++m)
      #pragma unroll
      for (int kc = 0; kc < 2; ++kc)
        pa[m][kc] = *(const bf16x8*)&p_s[(16 * m + lr) * PPAD + 32 * kc + 8 * lg];

    #pragma unroll
    for (int i = 0; i < 12; ++i) {
      const int cn = 16 * (12 * w + i);
      const unsigned short* bp2 = wuT + (size_t)(cn + lr) * KB + 8 * lg;
      const bf16x8 b0 = *(const bf16x8*)(bp2);
      const bf16x8 b1 = *(const bf16x8*)(bp2 + 32);
      f32x4 c0 = {0.f, 0.f, 0.f, 0.f};
      f32x4 c1 = {0.f, 0.f, 0.f, 0.f};
      c0 = __builtin_amdgcn_mfma_f32_16x16x32_bf16(pa[0][0], b0, c0, 0, 0, 0);
      c0 = __builtin_amdgcn_mfma_f32_16x16x32_bf16(pa[0][1], b1, c0, 0, 0, 0);
      c1 = __builtin_amdgcn_mfma_f32_16x16x32_bf16(pa[1][0], b0, c1, 0, 0, 0);
      c1 = __builtin_amdgcn_mfma_f32_16x16x32_bf16(pa[1][1], b1, c1, 0, 0, 0);
      const float bu = b_up[cn + lr];
      #pragma unroll
      for (int j = 0; j < 4; ++j) {
        const int r0 = 4 * lg + j;
        out[(size_t)(row0 + r0) * D_MODEL + cn + lr]      = c0[j] + bu;
        out[(size_t)(row0 + 16 + r0) * D_MODEL + cn + lr] = c1[j] + bu;
      }
    }
  }
}

// ---------------- launch ----------------
extern "C" void kernel_launch(void* const* d_in, const int* in_sizes, int n_in,
                              void* d_out, int out_size, void* d_ws, size_t ws_size,
                              hipStream_t stream) {
  const float* x     = (const float*)d_in[0];
  const float* gamma = (const float*)d_in[1];
  const float* beta  = (const float*)d_in[2];
  const float* wd    = (const float*)d_in[3];
  const float* bdown = (const float*)d_in[4];
  const float* wu    = (const float*)d_in[5];
  const float* bup   = (const float*)d_in[6];
  float* out = (float*)d_out;

  char* ws = (char*)d_ws;                       // needs 197,120 B
  unsigned short* wdT = (unsigned short*)ws;                    // 96 KiB
  unsigned short* wuT = (unsigned short*)(ws + 98304);          // 96 KiB
  float* s_arr = (float*)(ws + 196608);                         // 256 B
  float* t_arr = (float*)(ws + 196864);                         // 256 B

  const int rows = in_sizes[0] / D_MODEL;       // 32768

  adapter_prep<<<D_MODEL + 1, 64, 0, stream>>>(wd, wu, gamma, beta, bdown,
                                               wdT, wuT, s_arr, t_arr);
  adapter_main<<<rows / BM, NTHR, 0, stream>>>(x, s_arr, t_arr, wdT, wuT, bup, out);
}